// Round 4
// baseline (274.684 us; speedup 1.0000x reference)
//
#include <hip/hip_runtime.h>
#include <hip/hip_bf16.h>

// Problem constants (B=32, H=W=96, D=5, R=5, A=10, K=2, FA=4, T=7)
#define HW 9216
#define NB 32

// ---- float <-> order-preserving unsigned encoding for atomic min/max ----
__device__ inline unsigned fenc(float f){
    unsigned u = __float_as_uint(f);
    return (u & 0x80000000u) ? ~u : (u | 0x80000000u);
}
__device__ inline float fdec(unsigned u){
    return __uint_as_float((u & 0x80000000u) ? (u & 0x7fffffffu) : ~u);
}

// ---------------- Kernel 1: le = avgpool3x3(mf)+mf, global per-channel min/max ----------------
__global__ __launch_bounds__(256) void k_le(const float* __restrict__ mf,
                                            float* __restrict__ le,
                                            unsigned* __restrict__ mm /*[4]: max0,max1,min0,min1*/){
    int n = blockIdx.x * 256 + threadIdx.x;        // n < NB*2*HW
    int p = n % HW;
    int bc = n / HW;
    int c = bc & 1;
    int h = p / 96, w = p % 96;
    const float* plane = mf + (size_t)bc * HW;
    float s = 0.f;
    #pragma unroll
    for(int dy=-1; dy<=1; ++dy){
        int y = h + dy;
        if((unsigned)y < 96u){
            #pragma unroll
            for(int dx=-1; dx<=1; ++dx){
                int x = w + dx;
                if((unsigned)x < 96u) s += plane[y*96 + x];
            }
        }
    }
    float v = s * (1.0f/9.0f) + plane[p];
    le[n] = v;

    float mx = v, mn = v;
    #pragma unroll
    for(int o=32; o; o>>=1){
        mx = fmaxf(mx, __shfl_xor(mx, o));
        mn = fminf(mn, __shfl_xor(mn, o));
    }
    __shared__ float smx[4], smn[4];
    int wv = threadIdx.x >> 6;
    if((threadIdx.x & 63) == 0){ smx[wv] = mx; smn[wv] = mn; }
    __syncthreads();
    if(threadIdx.x == 0){
        for(int i=1;i<4;i++){ mx = fmaxf(mx, smx[i]); mn = fminf(mn, smn[i]); }
        atomicMax(&mm[c],     fenc(mx));
        atomicMin(&mm[2 + c], fenc(mn));
    }
}

// ---------------- Kernel 2: df = LeakyReLU(conv3x3([norm(le), uf], Wd) + bd) ----------------
__global__ __launch_bounds__(256) void k_dirconv(const float* __restrict__ uf,
                                                 const float* __restrict__ le,
                                                 const unsigned* __restrict__ mm,
                                                 const float* __restrict__ Wdw,
                                                 const float* __restrict__ bdw,
                                                 float* __restrict__ df){
    __shared__ float sW[180];
    __shared__ float sb[4];
    for(int i=threadIdx.x; i<180; i+=256) sW[i] = Wdw[i];
    if(threadIdx.x < 4) sb[threadIdx.x] = bdw[threadIdx.x];
    __syncthreads();

    int n = blockIdx.x * 256 + threadIdx.x;        // n < NB*HW
    int b = n / HW, p = n % HW;
    int h = p / 96, w = p % 96;

    float mx0 = fdec(mm[0]), mx1 = fdec(mm[1]);
    float mn0 = fdec(mm[2]), mn1 = fdec(mm[3]);
    float sc0 = 2.f / (mx0 - mn0), sc1 = 2.f / (mx1 - mn1);
    float of0 = -1.f - mn0 * sc0,  of1 = -1.f - mn1 * sc1;

    float acc0 = sb[0], acc1 = sb[1], acc2 = sb[2], acc3 = sb[3];
    #pragma unroll
    for(int i=0;i<5;i++){
        #pragma unroll
        for(int ky=0; ky<3; ky++){
            int y = h + ky - 1;
            if((unsigned)y >= 96u) continue;
            #pragma unroll
            for(int kx=0; kx<3; kx++){
                int x = w + kx - 1;
                if((unsigned)x >= 96u) continue;
                float v;
                if(i < 2) v = le[((size_t)b*2 + i)*HW + y*96 + x] * (i ? sc1 : sc0) + (i ? of1 : of0);
                else      v = uf[((size_t)b*3 + (i-2))*HW + y*96 + x];
                acc0 += v * sW[((0*5+i)*3+ky)*3+kx];
                acc1 += v * sW[((1*5+i)*3+ky)*3+kx];
                acc2 += v * sW[((2*5+i)*3+ky)*3+kx];
                acc3 += v * sW[((3*5+i)*3+ky)*3+kx];
            }
        }
    }
    size_t ob = ((size_t)b*4)*HW + p;
    df[ob + 0*HW] = acc0 > 0.f ? acc0 : 0.01f*acc0;
    df[ob + 1*HW] = acc1 > 0.f ? acc1 : 0.01f*acc1;
    df[ob + 2*HW] = acc2 > 0.f ? acc2 : 0.01f*acc2;
    df[ob + 3*HW] = acc3 > 0.f ? acc3 : 0.01f*acc3;
}

// ---- masked categorical: lp at argmax, argmax (first max), entropy over valid ----
template<int N>
__device__ __forceinline__ void mcat(const float* x, unsigned mask, float& lp, int& a, float& en){
    float ml[N];
    #pragma unroll
    for(int i=0;i<N;i++) ml[i] = ((mask >> i) & 1u) ? x[i] : -1e9f;
    float m = ml[0]; int am = 0;
    #pragma unroll
    for(int i=1;i<N;i++) if(ml[i] > m){ m = ml[i]; am = i; }
    float S = 0.f, T = 0.f;
    #pragma unroll
    for(int i=0;i<N;i++){
        float d = ml[i] - m;
        float e = expf(d);         // invalid entries: exp(-1e9-m) == 0 exactly
        S += e; T += e * d;
    }
    float lS = logf(S);
    lp = -lS;                      // ml[argmax] == m  =>  lp = m - (m + log S)
    a  = am;
    en = lS - T / S;               // == -sum_valid p*lp  (exact when >=1 valid; unused otherwise)
}

// ---- per-position fused head computation (scalar; called 4x per thread) ----
__device__ __forceinline__ void do_pos(
    unsigned mvm, unsigned tv, unsigned pkm, unsigned digm,
    unsigned sd1, unsigned rc1, unsigned dn1, unsigned fam,
    float vfa, float vfb, float vfc, float vfd, float vfe,
    float da, float db, float dc, float dd,
    float fja, float fjb, float fjc, float fjd, float fje, float fjf,
    const float* __restrict__ sw,
    float& critic, float& tot_lp, float& tot_en, int& fact,
    int& tt_o, int& dir_o, int& res_o, int& amt_o, int& rep_o, int& um_o)
{
    float vf5[5] = {vfa, vfb, vfc, vfd, vfe};
    float d4[4]  = {da, db, dc, dd};
    float f6[6]  = {fja, fjb, fjc, fjd, fje, fjf};

    unsigned uat = (mvm ? 1u:0u) | ((tv ? 1u:0u)<<1) | ((pkm ? 1u:0u)<<2) | ((digm ? 1u:0u)<<3)
                 | (sd1<<4) | (rc1<<5) | (dn1<<6);

    // critic
    critic = sw[5];
    #pragma unroll
    for(int c=0;c<5;c++) critic += sw[c] * vf5[c];

    // factory masked argmax
    fact = 0; float fb = -3e38f;
    #pragma unroll
    for(int j=0;j<4;j++){
        float lg = sw[30+j];
        #pragma unroll
        for(int c=0;c<6;c++) lg += sw[6 + j*6 + c] * f6[c];
        float mlv = ((fam >> j) & 1u) ? lg : -1e9f;
        if(mlv > fb){ fb = mlv; fact = j; }
    }

    // unit act-type head
    float tl[7];
    #pragma unroll
    for(int i=0;i<7;i++){
        float s = sw[69+i];
        #pragma unroll
        for(int c=0;c<5;c++) s += sw[34 + i*5 + c] * vf5[c];
        tl[i] = s;
    }
    float t_lp, t_en; int tt;
    mcat<7>(tl, uat, t_lp, tt, t_en);

    float hl[10];

    #pragma unroll
    for(int i=0;i<5;i++){ float s = sw[96+i];
        #pragma unroll
        for(int c=0;c<4;c++) s += sw[76 + i*4 + c] * d4[c]; hl[i]=s; }
    float lpmv, enmv; int mvdir; mcat<5>(hl, mvm, lpmv, mvdir, enmv);

    #pragma unroll
    for(int i=0;i<5;i++){ float s = sw[121+i];
        #pragma unroll
        for(int c=0;c<4;c++) s += sw[101 + i*4 + c] * d4[c]; hl[i]=s; }
    unsigned trd = 0;
    #pragma unroll
    for(int d=0; d<5; d++) trd |= (unsigned)(((tv >> (5*d)) & 31u) != 0) << d;
    float lptd, entd; int trdir; mcat<5>(hl, trd, lptd, trdir, entd);

    #pragma unroll
    for(int i=0;i<5;i++){ float s = sw[146+i];
        #pragma unroll
        for(int c=0;c<4;c++) s += sw[126 + i*4 + c] * d4[c]; hl[i]=s; }
    float lptr, entr; int trres; mcat<5>(hl, (tv >> (trdir*5)) & 31u, lptr, trres, entr);

    #pragma unroll
    for(int i=0;i<10;i++){ float s = sw[191+i];
        #pragma unroll
        for(int c=0;c<4;c++) s += sw[151 + i*4 + c] * d4[c]; hl[i]=s; }
    float lpta, enta; int tramt; mcat<10>(hl, 0x3FFu, lpta, tramt, enta);

    #pragma unroll
    for(int i=0;i<5;i++){ float s = sw[221+i];
        #pragma unroll
        for(int c=0;c<4;c++) s += sw[201 + i*4 + c] * d4[c]; hl[i]=s; }
    float lppr, enpr; int pkres; mcat<5>(hl, pkm, lppr, pkres, enpr);

    #pragma unroll
    for(int i=0;i<10;i++){ float s = sw[266+i];
        #pragma unroll
        for(int c=0;c<4;c++) s += sw[226 + i*4 + c] * d4[c]; hl[i]=s; }
    float lppa, enpa; int pkamt; mcat<10>(hl, 0x3FFu, lppa, pkamt, enpa);

    #pragma unroll
    for(int i=0;i<10;i++){ float s = sw[316+i];
        #pragma unroll
        for(int c=0;c<4;c++) s += sw[276 + i*4 + c] * d4[c]; hl[i]=s; }
    float lpra, enra; int rcamt; mcat<10>(hl, 0x3FFu, lpra, rcamt, enra);

    #pragma unroll
    for(int i=0;i<2;i++){ float s = sw[334+i];
        #pragma unroll
        for(int c=0;c<4;c++) s += sw[326 + i*4 + c] * d4[c]; hl[i]=s; }
    float lpdg, endg; int dgrep; mcat<2>(hl, digm, lpdg, dgrep, endg);

    float lps = 0.f, ens = 0.f; int dir = 0, res = 0, amt = 0, rep = 0;
    switch(tt){
        case 0: lps = lpmv;               ens = enmv;               dir = mvdir; break;
        case 1: lps = lptd + lptr + lpta; ens = entd + entr + enta; dir = trdir; res = trres; amt = tramt; break;
        case 2: lps = lppr + lppa;        ens = enpr + enpa;        res = pkres; amt = pkamt; break;
        case 3: lps = lpdg;               ens = endg;               rep = dgrep; break;
        case 5: lps = lpra;               ens = enra;               amt = rcamt; break;
        default: break;
    }
    tot_lp = t_lp + lps;
    tot_en = t_en + ens;
    tt_o = tt; dir_o = dir; res_o = res; amt_o = amt; rep_o = rep;
    um_o = (uat != 0);
}

// ---------------- Kernel 3: fused heads, 4 positions per thread ----------------
__global__ __launch_bounds__(256) void k_main(
    const float* __restrict__ mf, const float* __restrict__ uf, const float* __restrict__ ff,
    const int* __restrict__ loc,
    const int* __restrict__ vaM, const int* __restrict__ vaT, const int* __restrict__ vaP,
    const int* __restrict__ vaD, const int* __restrict__ vaS, const int* __restrict__ vaR,
    const int* __restrict__ vaN, const int* __restrict__ vaF,
    const float* Wc, const float* bc, const float* Wf, const float* bf,
    const float* Wt, const float* bt, const float* Wmd, const float* bmd,
    const float* Wtd, const float* btd, const float* Wtr, const float* btr,
    const float* Wta, const float* bta, const float* Wpr, const float* bpr,
    const float* Wpa, const float* bpa, const float* Wra, const float* bra,
    const float* Wdr, const float* bdr,
    const float* __restrict__ df,
    float* __restrict__ crm, float* __restrict__ lpm, float* __restrict__ enm,
    int* __restrict__ idx, float* __restrict__ out)
{
    __shared__ float sw[336];
    {
        int t = threadIdx.x;
        #define CPW(off, src, n) for(int i=t;i<(n);i+=256) sw[(off)+i]=(src)[i];
        CPW(0,Wc,5)    CPW(5,bc,1)    CPW(6,Wf,24)   CPW(30,bf,4)
        CPW(34,Wt,35)  CPW(69,bt,7)   CPW(76,Wmd,20) CPW(96,bmd,5)
        CPW(101,Wtd,20) CPW(121,btd,5) CPW(126,Wtr,20) CPW(146,btr,5)
        CPW(151,Wta,40) CPW(191,bta,10) CPW(201,Wpr,20) CPW(221,bpr,5)
        CPW(226,Wpa,40) CPW(266,bpa,10) CPW(276,Wra,40) CPW(316,bra,10)
        CPW(326,Wdr,8)  CPW(334,bdr,2)
        #undef CPW
    }
    __syncthreads();

    int n4 = blockIdx.x * 256 + threadIdx.x;       // < NB*HW/4 = 73728
    int b  = n4 / (HW/4);
    int p0 = (n4 - b*(HW/4)) * 4;

    // ---- vectorized mask streaming: int4 = 4 consecutive positions ----
    unsigned mvmA[4] = {0,0,0,0};
    {
        const int* vmb = vaM + (size_t)b*10*HW + p0;
        #pragma unroll
        for(int d=0; d<5; d++){
            int4 k0 = *(const int4*)(vmb + (size_t)(2*d+0)*HW);
            int4 k1 = *(const int4*)(vmb + (size_t)(2*d+1)*HW);
            mvmA[0] |= (unsigned)((k0.x|k1.x)!=0) << d;
            mvmA[1] |= (unsigned)((k0.y|k1.y)!=0) << d;
            mvmA[2] |= (unsigned)((k0.z|k1.z)!=0) << d;
            mvmA[3] |= (unsigned)((k0.w|k1.w)!=0) << d;
        }
    }
    unsigned tvA[4] = {0,0,0,0};
    {
        const int* vtb = vaT + (size_t)b*250*HW + p0;
        #pragma unroll 5
        for(int g=0; g<25; g++){
            int4 acc = *(const int4*)(vtb + (size_t)(g*10)*HW);
            #pragma unroll
            for(int a=1; a<10; a++){
                int4 t = *(const int4*)(vtb + (size_t)(g*10+a)*HW);
                acc.x|=t.x; acc.y|=t.y; acc.z|=t.z; acc.w|=t.w;
            }
            tvA[0] |= (unsigned)(acc.x!=0) << g;
            tvA[1] |= (unsigned)(acc.y!=0) << g;
            tvA[2] |= (unsigned)(acc.z!=0) << g;
            tvA[3] |= (unsigned)(acc.w!=0) << g;
        }
    }
    unsigned pkmA[4] = {0,0,0,0};
    {
        const int* vpb = vaP + (size_t)b*50*HW + p0;
        #pragma unroll
        for(int r=0; r<5; r++){
            int4 acc = *(const int4*)(vpb + (size_t)(r*10)*HW);
            #pragma unroll
            for(int a=1; a<10; a++){
                int4 t = *(const int4*)(vpb + (size_t)(r*10+a)*HW);
                acc.x|=t.x; acc.y|=t.y; acc.z|=t.z; acc.w|=t.w;
            }
            pkmA[0] |= (unsigned)(acc.x!=0) << r;
            pkmA[1] |= (unsigned)(acc.y!=0) << r;
            pkmA[2] |= (unsigned)(acc.z!=0) << r;
            pkmA[3] |= (unsigned)(acc.w!=0) << r;
        }
    }
    unsigned digA[4], sdA[4], rcA[4], dnA[4], famA[4];
    {
        const int* vdb = vaD + (size_t)b*2*HW + p0;
        int4 k0 = *(const int4*)(vdb);
        int4 k1 = *(const int4*)(vdb + (size_t)HW);
        digA[0] = (unsigned)(k0.x!=0) | ((unsigned)(k1.x!=0)<<1);
        digA[1] = (unsigned)(k0.y!=0) | ((unsigned)(k1.y!=0)<<1);
        digA[2] = (unsigned)(k0.z!=0) | ((unsigned)(k1.z!=0)<<1);
        digA[3] = (unsigned)(k0.w!=0) | ((unsigned)(k1.w!=0)<<1);
    }
    {
        const int* vsb = vaS + (size_t)b*2*HW + p0;
        int4 k0 = *(const int4*)(vsb);
        int4 k1 = *(const int4*)(vsb + (size_t)HW);
        sdA[0]=(unsigned)((k0.x|k1.x)!=0); sdA[1]=(unsigned)((k0.y|k1.y)!=0);
        sdA[2]=(unsigned)((k0.z|k1.z)!=0); sdA[3]=(unsigned)((k0.w|k1.w)!=0);
    }
    {
        const int* vrb = vaR + (size_t)b*2*HW + p0;
        int4 k0 = *(const int4*)(vrb);
        int4 k1 = *(const int4*)(vrb + (size_t)HW);
        rcA[0]=(unsigned)((k0.x|k1.x)!=0); rcA[1]=(unsigned)((k0.y|k1.y)!=0);
        rcA[2]=(unsigned)((k0.z|k1.z)!=0); rcA[3]=(unsigned)((k0.w|k1.w)!=0);
    }
    {
        int4 k0 = *(const int4*)(vaN + (size_t)b*HW + p0);
        dnA[0]=(unsigned)(k0.x!=0); dnA[1]=(unsigned)(k0.y!=0);
        dnA[2]=(unsigned)(k0.z!=0); dnA[3]=(unsigned)(k0.w!=0);
    }
    {
        const int* vfb = vaF + (size_t)b*4*HW + p0;
        famA[0]=famA[1]=famA[2]=famA[3]=0;
        #pragma unroll
        for(int j=0; j<4; j++){
            int4 k = *(const int4*)(vfb + (size_t)j*HW);
            famA[0] |= (unsigned)(k.x!=0) << j;
            famA[1] |= (unsigned)(k.y!=0) << j;
            famA[2] |= (unsigned)(k.z!=0) << j;
            famA[3] |= (unsigned)(k.w!=0) << j;
        }
    }
    int liA[4];
    {
        int4 li = *(const int4*)(loc + ((size_t)b*2 + 1)*HW + p0);
        liA[0]=li.x; liA[1]=li.y; liA[2]=li.z; liA[3]=li.w;
    }

    // ---- vectorized feature loads ----
    const float4 m0 = *(const float4*)(mf + ((size_t)b*2+0)*HW + p0);
    const float4 m1 = *(const float4*)(mf + ((size_t)b*2+1)*HW + p0);
    const float4 u0 = *(const float4*)(uf + ((size_t)b*3+0)*HW + p0);
    const float4 u1 = *(const float4*)(uf + ((size_t)b*3+1)*HW + p0);
    const float4 u2 = *(const float4*)(uf + ((size_t)b*3+2)*HW + p0);
    const float4 q0 = *(const float4*)(df + ((size_t)b*4+0)*HW + p0);
    const float4 q1 = *(const float4*)(df + ((size_t)b*4+1)*HW + p0);
    const float4 q2 = *(const float4*)(df + ((size_t)b*4+2)*HW + p0);
    const float4 q3 = *(const float4*)(df + ((size_t)b*4+3)*HW + p0);
    const float4 f0 = *(const float4*)(ff + ((size_t)b*6+0)*HW + p0);
    const float4 f1 = *(const float4*)(ff + ((size_t)b*6+1)*HW + p0);
    const float4 f2 = *(const float4*)(ff + ((size_t)b*6+2)*HW + p0);
    const float4 f3 = *(const float4*)(ff + ((size_t)b*6+3)*HW + p0);
    const float4 f4 = *(const float4*)(ff + ((size_t)b*6+4)*HW + p0);
    const float4 f5 = *(const float4*)(ff + ((size_t)b*6+5)*HW + p0);

    // ---- per-position head compute ----
    float crA[4], lpA[4], enA[4];
    int faA[4], ttA[4], dirA[4], resA[4], amtA[4], repA[4], umA[4];

    do_pos(mvmA[0], tvA[0], pkmA[0], digA[0], sdA[0], rcA[0], dnA[0], famA[0],
           m0.x, m1.x, u0.x, u1.x, u2.x, q0.x, q1.x, q2.x, q3.x,
           f0.x, f1.x, f2.x, f3.x, f4.x, f5.x, sw,
           crA[0], lpA[0], enA[0], faA[0], ttA[0], dirA[0], resA[0], amtA[0], repA[0], umA[0]);
    do_pos(mvmA[1], tvA[1], pkmA[1], digA[1], sdA[1], rcA[1], dnA[1], famA[1],
           m0.y, m1.y, u0.y, u1.y, u2.y, q0.y, q1.y, q2.y, q3.y,
           f0.y, f1.y, f2.y, f3.y, f4.y, f5.y, sw,
           crA[1], lpA[1], enA[1], faA[1], ttA[1], dirA[1], resA[1], amtA[1], repA[1], umA[1]);
    do_pos(mvmA[2], tvA[2], pkmA[2], digA[2], sdA[2], rcA[2], dnA[2], famA[2],
           m0.z, m1.z, u0.z, u1.z, u2.z, q0.z, q1.z, q2.z, q3.z,
           f0.z, f1.z, f2.z, f3.z, f4.z, f5.z, sw,
           crA[2], lpA[2], enA[2], faA[2], ttA[2], dirA[2], resA[2], amtA[2], repA[2], umA[2]);
    do_pos(mvmA[3], tvA[3], pkmA[3], digA[3], sdA[3], rcA[3], dnA[3], famA[3],
           m0.w, m1.w, u0.w, u1.w, u2.w, q0.w, q1.w, q2.w, q3.w,
           f0.w, f1.w, f2.w, f3.w, f4.w, f5.w, sw,
           crA[3], lpA[3], enA[3], faA[3], ttA[3], dirA[3], resA[3], amtA[3], repA[3], umA[3]);

    // ---- vectorized stores ----
    size_t q = (size_t)b*HW + p0;
    *(float4*)(crm + q) = make_float4(crA[0], crA[1], crA[2], crA[3]);
    *(float4*)(lpm + q) = make_float4(lpA[0], lpA[1], lpA[2], lpA[3]);
    *(float4*)(enm + q) = make_float4(enA[0], enA[1], enA[2], enA[3]);

    *(float4*)(out + 96000 + q) = make_float4(
        famA[0] ? (float)faA[0] : 0.f, famA[1] ? (float)faA[1] : 0.f,
        famA[2] ? (float)faA[2] : 0.f, famA[3] ? (float)faA[3] : 0.f);

    size_t ub = 390912 + (size_t)b*6*HW + p0;
    *(float4*)(out + ub + 0*HW) = make_float4(
        umA[0]?(float)ttA[0]:0.f, umA[1]?(float)ttA[1]:0.f, umA[2]?(float)ttA[2]:0.f, umA[3]?(float)ttA[3]:0.f);
    *(float4*)(out + ub + 1*HW) = make_float4(
        umA[0]?(float)dirA[0]:0.f, umA[1]?(float)dirA[1]:0.f, umA[2]?(float)dirA[2]:0.f, umA[3]?(float)dirA[3]:0.f);
    *(float4*)(out + ub + 2*HW) = make_float4(
        umA[0]?(float)resA[0]:0.f, umA[1]?(float)resA[1]:0.f, umA[2]?(float)resA[2]:0.f, umA[3]?(float)resA[3]:0.f);
    *(float4*)(out + ub + 3*HW) = make_float4(
        umA[0]?(float)amtA[0]:0.f, umA[1]?(float)amtA[1]:0.f, umA[2]?(float)amtA[2]:0.f, umA[3]?(float)amtA[3]:0.f);
    *(float4*)(out + ub + 4*HW) = make_float4(
        umA[0]?(float)repA[0]:0.f, umA[1]?(float)repA[1]:0.f, umA[2]?(float)repA[2]:0.f, umA[3]?(float)repA[3]:0.f);
    *(float4*)(out + ub + 5*HW) = make_float4(
        umA[0]?1.f:0.f, umA[1]?1.f:0.f, umA[2]?1.f:0.f, umA[3]?1.f:0.f);

    // ---- scatter winner: numpy last-write-wins == max linear position per (b,id) ----
    #pragma unroll
    for(int j=0; j<4; j++){
        if(umA[j]){
            int id = liA[j] + 10;
            if((unsigned)id < 1000u) atomicMax(&idx[b*1000 + id], p0 + j);
        }
    }
}

// ---------------- Kernel 4: resolve [B,1000] scatters ----------------
__global__ __launch_bounds__(256) void k_gather(const int* __restrict__ idx,
                                                const float* __restrict__ crm,
                                                const float* __restrict__ lpm,
                                                const float* __restrict__ enm,
                                                float* __restrict__ out){
    int j = blockIdx.x * 256 + threadIdx.x;
    if(j >= 32000) return;
    int b = j / 1000;
    int pos = idx[j];
    float lp = 0.f, cv = 0.f, en = 0.f;
    if(pos >= 0){
        size_t q = (size_t)b*HW + pos;
        lp = lpm[q]; cv = crm[q]; en = enm[q];
    }
    out[j]          = lp;
    out[32000 + j]  = cv;
    out[64000 + j]  = en;
}

extern "C" void kernel_launch(void* const* d_in, const int* in_sizes, int n_in,
                              void* d_out, int out_size, void* d_ws, size_t ws_size,
                              hipStream_t stream) {
    const float* mf  = (const float*)d_in[1];
    const float* ffp = (const float*)d_in[2];
    const float* ufp = (const float*)d_in[3];
    const int*   loc = (const int*)d_in[4];
    const int* vaM = (const int*)d_in[5];
    const int* vaT = (const int*)d_in[6];
    const int* vaP = (const int*)d_in[7];
    const int* vaD = (const int*)d_in[8];
    const int* vaS = (const int*)d_in[9];
    const int* vaR = (const int*)d_in[10];
    const int* vaN = (const int*)d_in[11];
    const int* vaF = (const int*)d_in[12];
    const float *Wf=(const float*)d_in[13], *bf=(const float*)d_in[14];
    const float *Wc=(const float*)d_in[15], *bc=(const float*)d_in[16];
    const float *Wdw=(const float*)d_in[17], *bdw=(const float*)d_in[18];
    const float *Wt=(const float*)d_in[19], *bt=(const float*)d_in[20];
    const float *Wmd=(const float*)d_in[21], *bmd=(const float*)d_in[22];
    const float *Wtd=(const float*)d_in[23], *btd=(const float*)d_in[24];
    const float *Wtr=(const float*)d_in[25], *btr=(const float*)d_in[26];
    const float *Wta=(const float*)d_in[27], *bta=(const float*)d_in[28];
    const float *Wpr=(const float*)d_in[29], *bpr=(const float*)d_in[30];
    const float *Wpa=(const float*)d_in[31], *bpa=(const float*)d_in[32];
    const float *Wra=(const float*)d_in[33], *bra=(const float*)d_in[34];
    const float *Wdr=(const float*)d_in[35], *bdr=(const float*)d_in[36];

    char* ws = (char*)d_ws;
    float* le  = (float*)(ws + 0);                 // 32*2*9216*4  = 2,359,296
    float* df  = (float*)(ws + 2359296);           // 32*4*9216*4  = 4,718,592
    float* crm = (float*)(ws + 7077888);           // 32*9216*4    = 1,179,648
    float* lpm = (float*)(ws + 8257536);
    float* enm = (float*)(ws + 9437184);
    int*   idx = (int*)(ws + 10616832);            // 32*1000*4    = 128,000
    unsigned* mm = (unsigned*)(ws + 10744832);     // 4 words

    hipMemsetAsync(mm, 0x00, 8, stream);           // max accumulators -> encoded -inf floor
    hipMemsetAsync((char*)mm + 8, 0xFF, 8, stream);// min accumulators -> encoded +inf ceil
    hipMemsetAsync(idx, 0xFF, 128000, stream);     // scatter winners -> -1

    k_le<<<dim3(2304), dim3(256), 0, stream>>>(mf, le, mm);
    k_dirconv<<<dim3(1152), dim3(256), 0, stream>>>(ufp, le, mm, Wdw, bdw, df);
    k_main<<<dim3(288), dim3(256), 0, stream>>>(
        mf, ufp, ffp, loc, vaM, vaT, vaP, vaD, vaS, vaR, vaN, vaF,
        Wc, bc, Wf, bf, Wt, bt, Wmd, bmd, Wtd, btd, Wtr, btr,
        Wta, bta, Wpr, bpr, Wpa, bpa, Wra, bra, Wdr, bdr,
        df, crm, lpm, enm, idx, (float*)d_out);
    k_gather<<<dim3(125), dim3(256), 0, stream>>>(idx, crm, lpm, enm, (float*)d_out);
}

// Round 5
// 210.787 us; speedup vs baseline: 1.3031x; 1.3031x over previous
//
#include <hip/hip_runtime.h>
#include <hip/hip_bf16.h>

// Problem constants (B=32, H=W=96, D=5, R=5, A=10, K=2, FA=4, T=7)
#define HW 9216
#define NB 32

// ---- float <-> order-preserving unsigned encoding for atomic min/max ----
__device__ inline unsigned fenc(float f){
    unsigned u = __float_as_uint(f);
    return (u & 0x80000000u) ? ~u : (u | 0x80000000u);
}
__device__ inline float fdec(unsigned u){
    return __uint_as_float((u & 0x80000000u) ? (u & 0x7fffffffu) : ~u);
}

// ---------------- Kernel 1: le = avgpool3x3(mf)+mf, global per-channel min/max ----------------
__global__ __launch_bounds__(256) void k_le(const float* __restrict__ mf,
                                            float* __restrict__ le,
                                            unsigned* __restrict__ mm /*[4]: max0,max1,min0,min1*/){
    int n = blockIdx.x * 256 + threadIdx.x;        // n < NB*2*HW
    int p = n % HW;
    int bc = n / HW;
    int c = bc & 1;
    int h = p / 96, w = p % 96;
    const float* plane = mf + (size_t)bc * HW;
    float s = 0.f;
    #pragma unroll
    for(int dy=-1; dy<=1; ++dy){
        int y = h + dy;
        if((unsigned)y < 96u){
            #pragma unroll
            for(int dx=-1; dx<=1; ++dx){
                int x = w + dx;
                if((unsigned)x < 96u) s += plane[y*96 + x];
            }
        }
    }
    float v = s * (1.0f/9.0f) + plane[p];
    le[n] = v;

    float mx = v, mn = v;
    #pragma unroll
    for(int o=32; o; o>>=1){
        mx = fmaxf(mx, __shfl_xor(mx, o));
        mn = fminf(mn, __shfl_xor(mn, o));
    }
    __shared__ float smx[4], smn[4];
    int wv = threadIdx.x >> 6;
    if((threadIdx.x & 63) == 0){ smx[wv] = mx; smn[wv] = mn; }
    __syncthreads();
    if(threadIdx.x == 0){
        for(int i=1;i<4;i++){ mx = fmaxf(mx, smx[i]); mn = fminf(mn, smn[i]); }
        atomicMax(&mm[c],     fenc(mx));
        atomicMin(&mm[2 + c], fenc(mn));
    }
}

// ---------------- Kernel 2: df = LeakyReLU(conv3x3([norm(le), uf], Wd) + bd) ----------------
__global__ __launch_bounds__(256) void k_dirconv(const float* __restrict__ uf,
                                                 const float* __restrict__ le,
                                                 const unsigned* __restrict__ mm,
                                                 const float* __restrict__ Wdw,
                                                 const float* __restrict__ bdw,
                                                 float* __restrict__ df){
    __shared__ float sW[180];
    __shared__ float sb[4];
    for(int i=threadIdx.x; i<180; i+=256) sW[i] = Wdw[i];
    if(threadIdx.x < 4) sb[threadIdx.x] = bdw[threadIdx.x];
    __syncthreads();

    int n = blockIdx.x * 256 + threadIdx.x;        // n < NB*HW
    int b = n / HW, p = n % HW;
    int h = p / 96, w = p % 96;

    float mx0 = fdec(mm[0]), mx1 = fdec(mm[1]);
    float mn0 = fdec(mm[2]), mn1 = fdec(mm[3]);
    float sc0 = 2.f / (mx0 - mn0), sc1 = 2.f / (mx1 - mn1);
    float of0 = -1.f - mn0 * sc0,  of1 = -1.f - mn1 * sc1;

    float acc0 = sb[0], acc1 = sb[1], acc2 = sb[2], acc3 = sb[3];
    #pragma unroll
    for(int i=0;i<5;i++){
        #pragma unroll
        for(int ky=0; ky<3; ky++){
            int y = h + ky - 1;
            if((unsigned)y >= 96u) continue;
            #pragma unroll
            for(int kx=0; kx<3; kx++){
                int x = w + kx - 1;
                if((unsigned)x >= 96u) continue;
                float v;
                if(i < 2) v = le[((size_t)b*2 + i)*HW + y*96 + x] * (i ? sc1 : sc0) + (i ? of1 : of0);
                else      v = uf[((size_t)b*3 + (i-2))*HW + y*96 + x];
                acc0 += v * sW[((0*5+i)*3+ky)*3+kx];
                acc1 += v * sW[((1*5+i)*3+ky)*3+kx];
                acc2 += v * sW[((2*5+i)*3+ky)*3+kx];
                acc3 += v * sW[((3*5+i)*3+ky)*3+kx];
            }
        }
    }
    size_t ob = ((size_t)b*4)*HW + p;
    df[ob + 0*HW] = acc0 > 0.f ? acc0 : 0.01f*acc0;
    df[ob + 1*HW] = acc1 > 0.f ? acc1 : 0.01f*acc1;
    df[ob + 2*HW] = acc2 > 0.f ? acc2 : 0.01f*acc2;
    df[ob + 3*HW] = acc3 > 0.f ? acc3 : 0.01f*acc3;
}

// ---------------- Kernel 3: LEAN mask stream -> compact bitmasks ----------------
// per position: tvm = 25-bit transfer (dir,res) any-over-A
//               pkd = mvm(5) | pkm(5)<<5 | dig(2)<<10 | sd<<12 | rc<<13 | dn<<14 | fam(4)<<15
__global__ __launch_bounds__(256) void k_masks(
    const int* __restrict__ vaM, const int* __restrict__ vaT, const int* __restrict__ vaP,
    const int* __restrict__ vaD, const int* __restrict__ vaS, const int* __restrict__ vaR,
    const int* __restrict__ vaN, const int* __restrict__ vaF,
    unsigned* __restrict__ tvm, unsigned* __restrict__ pkd)
{
    int n4 = blockIdx.x * 256 + threadIdx.x;       // < NB*HW/4 = 73728
    int b  = n4 / (HW/4);
    int p0 = (n4 - b*(HW/4)) * 4;

    unsigned tvA[4] = {0,0,0,0};
    {
        const int* vtb = vaT + (size_t)b*250*HW + p0;
        #pragma unroll 5
        for(int g=0; g<25; g++){
            int4 acc = *(const int4*)(vtb + (size_t)(g*10)*HW);
            #pragma unroll
            for(int a=1; a<10; a++){
                int4 t = *(const int4*)(vtb + (size_t)(g*10+a)*HW);
                acc.x|=t.x; acc.y|=t.y; acc.z|=t.z; acc.w|=t.w;
            }
            tvA[0] |= (unsigned)(acc.x!=0) << g;
            tvA[1] |= (unsigned)(acc.y!=0) << g;
            tvA[2] |= (unsigned)(acc.z!=0) << g;
            tvA[3] |= (unsigned)(acc.w!=0) << g;
        }
    }
    unsigned pkA[4] = {0,0,0,0};
    {   // mvm bits 0..4
        const int* vmb = vaM + (size_t)b*10*HW + p0;
        #pragma unroll
        for(int d=0; d<5; d++){
            int4 k0 = *(const int4*)(vmb + (size_t)(2*d+0)*HW);
            int4 k1 = *(const int4*)(vmb + (size_t)(2*d+1)*HW);
            pkA[0] |= (unsigned)((k0.x|k1.x)!=0) << d;
            pkA[1] |= (unsigned)((k0.y|k1.y)!=0) << d;
            pkA[2] |= (unsigned)((k0.z|k1.z)!=0) << d;
            pkA[3] |= (unsigned)((k0.w|k1.w)!=0) << d;
        }
    }
    {   // pkm bits 5..9
        const int* vpb = vaP + (size_t)b*50*HW + p0;
        #pragma unroll
        for(int r=0; r<5; r++){
            int4 acc = *(const int4*)(vpb + (size_t)(r*10)*HW);
            #pragma unroll
            for(int a=1; a<10; a++){
                int4 t = *(const int4*)(vpb + (size_t)(r*10+a)*HW);
                acc.x|=t.x; acc.y|=t.y; acc.z|=t.z; acc.w|=t.w;
            }
            pkA[0] |= (unsigned)(acc.x!=0) << (5+r);
            pkA[1] |= (unsigned)(acc.y!=0) << (5+r);
            pkA[2] |= (unsigned)(acc.z!=0) << (5+r);
            pkA[3] |= (unsigned)(acc.w!=0) << (5+r);
        }
    }
    {   // dig bits 10,11
        const int* vdb = vaD + (size_t)b*2*HW + p0;
        int4 k0 = *(const int4*)(vdb);
        int4 k1 = *(const int4*)(vdb + (size_t)HW);
        pkA[0] |= ((unsigned)(k0.x!=0)<<10) | ((unsigned)(k1.x!=0)<<11);
        pkA[1] |= ((unsigned)(k0.y!=0)<<10) | ((unsigned)(k1.y!=0)<<11);
        pkA[2] |= ((unsigned)(k0.z!=0)<<10) | ((unsigned)(k1.z!=0)<<11);
        pkA[3] |= ((unsigned)(k0.w!=0)<<10) | ((unsigned)(k1.w!=0)<<11);
    }
    {   // sd bit 12
        const int* vsb = vaS + (size_t)b*2*HW + p0;
        int4 k0 = *(const int4*)(vsb);
        int4 k1 = *(const int4*)(vsb + (size_t)HW);
        pkA[0] |= (unsigned)((k0.x|k1.x)!=0)<<12; pkA[1] |= (unsigned)((k0.y|k1.y)!=0)<<12;
        pkA[2] |= (unsigned)((k0.z|k1.z)!=0)<<12; pkA[3] |= (unsigned)((k0.w|k1.w)!=0)<<12;
    }
    {   // rc bit 13
        const int* vrb = vaR + (size_t)b*2*HW + p0;
        int4 k0 = *(const int4*)(vrb);
        int4 k1 = *(const int4*)(vrb + (size_t)HW);
        pkA[0] |= (unsigned)((k0.x|k1.x)!=0)<<13; pkA[1] |= (unsigned)((k0.y|k1.y)!=0)<<13;
        pkA[2] |= (unsigned)((k0.z|k1.z)!=0)<<13; pkA[3] |= (unsigned)((k0.w|k1.w)!=0)<<13;
    }
    {   // dn bit 14
        int4 k0 = *(const int4*)(vaN + (size_t)b*HW + p0);
        pkA[0] |= (unsigned)(k0.x!=0)<<14; pkA[1] |= (unsigned)(k0.y!=0)<<14;
        pkA[2] |= (unsigned)(k0.z!=0)<<14; pkA[3] |= (unsigned)(k0.w!=0)<<14;
    }
    {   // fam bits 15..18
        const int* vfb = vaF + (size_t)b*4*HW + p0;
        #pragma unroll
        for(int j=0; j<4; j++){
            int4 k = *(const int4*)(vfb + (size_t)j*HW);
            pkA[0] |= (unsigned)(k.x!=0) << (15+j);
            pkA[1] |= (unsigned)(k.y!=0) << (15+j);
            pkA[2] |= (unsigned)(k.z!=0) << (15+j);
            pkA[3] |= (unsigned)(k.w!=0) << (15+j);
        }
    }
    size_t q = (size_t)b*HW + p0;
    *(uint4*)(tvm + q) = make_uint4(tvA[0], tvA[1], tvA[2], tvA[3]);
    *(uint4*)(pkd + q) = make_uint4(pkA[0], pkA[1], pkA[2], pkA[3]);
}

// ---- masked categorical: lp at argmax, argmax (first max), entropy over valid ----
template<int N>
__device__ __forceinline__ void mcat(const float* x, unsigned mask, float& lp, int& a, float& en){
    float ml[N];
    #pragma unroll
    for(int i=0;i<N;i++) ml[i] = ((mask >> i) & 1u) ? x[i] : -1e9f;
    float m = ml[0]; int am = 0;
    #pragma unroll
    for(int i=1;i<N;i++) if(ml[i] > m){ m = ml[i]; am = i; }
    float S = 0.f, T = 0.f;
    #pragma unroll
    for(int i=0;i<N;i++){
        float d = ml[i] - m;
        float e = expf(d);         // invalid entries: exp(-1e9-m) == 0 exactly
        S += e; T += e * d;
    }
    float lS = logf(S);
    lp = -lS;                      // ml[argmax] == m  =>  lp = m - (m + log S)
    a  = am;
    en = lS - T / S;               // == -sum_valid p*lp  (exact when >=1 valid; unused otherwise)
}

// ---------------- Kernel 4: per-position heads (compact masks in) ----------------
__global__ __launch_bounds__(256) void k_heads(
    const float* __restrict__ mf, const float* __restrict__ uf, const float* __restrict__ ff,
    const int* __restrict__ loc,
    const unsigned* __restrict__ tvm, const unsigned* __restrict__ pkd,
    const float* Wc, const float* bc, const float* Wf, const float* bf,
    const float* Wt, const float* bt, const float* Wmd, const float* bmd,
    const float* Wtd, const float* btd, const float* Wtr, const float* btr,
    const float* Wta, const float* bta, const float* Wpr, const float* bpr,
    const float* Wpa, const float* bpa, const float* Wra, const float* bra,
    const float* Wdr, const float* bdr,
    const float* __restrict__ df,
    float* __restrict__ crm, float* __restrict__ lpm, float* __restrict__ enm,
    int* __restrict__ idx, float* __restrict__ out)
{
    __shared__ float sw[336];
    {
        int t = threadIdx.x;
        #define CPW(off, src, n) for(int i=t;i<(n);i+=256) sw[(off)+i]=(src)[i];
        CPW(0,Wc,5)    CPW(5,bc,1)    CPW(6,Wf,24)   CPW(30,bf,4)
        CPW(34,Wt,35)  CPW(69,bt,7)   CPW(76,Wmd,20) CPW(96,bmd,5)
        CPW(101,Wtd,20) CPW(121,btd,5) CPW(126,Wtr,20) CPW(146,btr,5)
        CPW(151,Wta,40) CPW(191,bta,10) CPW(201,Wpr,20) CPW(221,bpr,5)
        CPW(226,Wpa,40) CPW(266,bpa,10) CPW(276,Wra,40) CPW(316,bra,10)
        CPW(326,Wdr,8)  CPW(334,bdr,2)
        #undef CPW
    }
    __syncthreads();

    int n = blockIdx.x * 256 + threadIdx.x;        // n < NB*HW
    int b = n / HW, p = n % HW;
    size_t q = (size_t)b*HW + p;

    unsigned tv = tvm[q];
    unsigned pk = pkd[q];
    unsigned mvm  = pk & 31u;
    unsigned pkm  = (pk >> 5) & 31u;
    unsigned digm = (pk >> 10) & 3u;
    unsigned sd1  = (pk >> 12) & 1u;
    unsigned rc1  = (pk >> 13) & 1u;
    unsigned dn1  = (pk >> 14) & 1u;
    unsigned fam  = (pk >> 15) & 15u;

    unsigned uat = (mvm ? 1u:0u) | ((tv ? 1u:0u)<<1) | ((pkm ? 1u:0u)<<2) | ((digm ? 1u:0u)<<3)
                 | (sd1<<4) | (rc1<<5) | (dn1<<6);
    bool um = (uat != 0);

    // features
    float vf5[5];
    vf5[0] = mf[((size_t)b*2+0)*HW + p];
    vf5[1] = mf[((size_t)b*2+1)*HW + p];
    vf5[2] = uf[((size_t)b*3+0)*HW + p];
    vf5[3] = uf[((size_t)b*3+1)*HW + p];
    vf5[4] = uf[((size_t)b*3+2)*HW + p];
    float d4[4];
    #pragma unroll
    for(int o=0;o<4;o++) d4[o] = df[((size_t)b*4+o)*HW + p];
    float f6[6];
    #pragma unroll
    for(int j=0;j<6;j++) f6[j] = ff[((size_t)b*6+j)*HW + p];

    // critic
    float critic = sw[5];
    #pragma unroll
    for(int c=0;c<5;c++) critic += sw[c] * vf5[c];

    // factory masked argmax
    int fact = 0; float fb = -3e38f;
    #pragma unroll
    for(int j=0;j<4;j++){
        float lg = sw[30+j];
        #pragma unroll
        for(int c=0;c<6;c++) lg += sw[6 + j*6 + c] * f6[c];
        float mlv = ((fam >> j) & 1u) ? lg : -1e9f;
        if(mlv > fb){ fb = mlv; fact = j; }
    }

    // act-type head
    float tl[7];
    #pragma unroll
    for(int i=0;i<7;i++){
        float s = sw[69+i];
        #pragma unroll
        for(int c=0;c<5;c++) s += sw[34 + i*5 + c] * vf5[c];
        tl[i] = s;
    }
    float t_lp, t_en; int tt;
    mcat<7>(tl, uat, t_lp, tt, t_en);

    float hl[10];

    #pragma unroll
    for(int i=0;i<5;i++){ float s = sw[96+i];
        #pragma unroll
        for(int c=0;c<4;c++) s += sw[76 + i*4 + c] * d4[c]; hl[i]=s; }
    float lpmv, enmv; int mvdir; mcat<5>(hl, mvm, lpmv, mvdir, enmv);

    #pragma unroll
    for(int i=0;i<5;i++){ float s = sw[121+i];
        #pragma unroll
        for(int c=0;c<4;c++) s += sw[101 + i*4 + c] * d4[c]; hl[i]=s; }
    unsigned trd = 0;
    #pragma unroll
    for(int d=0; d<5; d++) trd |= (unsigned)(((tv >> (5*d)) & 31u) != 0) << d;
    float lptd, entd; int trdir; mcat<5>(hl, trd, lptd, trdir, entd);

    #pragma unroll
    for(int i=0;i<5;i++){ float s = sw[146+i];
        #pragma unroll
        for(int c=0;c<4;c++) s += sw[126 + i*4 + c] * d4[c]; hl[i]=s; }
    float lptr, entr; int trres; mcat<5>(hl, (tv >> (trdir*5)) & 31u, lptr, trres, entr);

    #pragma unroll
    for(int i=0;i<10;i++){ float s = sw[191+i];
        #pragma unroll
        for(int c=0;c<4;c++) s += sw[151 + i*4 + c] * d4[c]; hl[i]=s; }
    float lpta, enta; int tramt; mcat<10>(hl, 0x3FFu, lpta, tramt, enta);

    #pragma unroll
    for(int i=0;i<5;i++){ float s = sw[221+i];
        #pragma unroll
        for(int c=0;c<4;c++) s += sw[201 + i*4 + c] * d4[c]; hl[i]=s; }
    float lppr, enpr; int pkres; mcat<5>(hl, pkm, lppr, pkres, enpr);

    #pragma unroll
    for(int i=0;i<10;i++){ float s = sw[266+i];
        #pragma unroll
        for(int c=0;c<4;c++) s += sw[226 + i*4 + c] * d4[c]; hl[i]=s; }
    float lppa, enpa; int pkamt; mcat<10>(hl, 0x3FFu, lppa, pkamt, enpa);

    #pragma unroll
    for(int i=0;i<10;i++){ float s = sw[316+i];
        #pragma unroll
        for(int c=0;c<4;c++) s += sw[276 + i*4 + c] * d4[c]; hl[i]=s; }
    float lpra, enra; int rcamt; mcat<10>(hl, 0x3FFu, lpra, rcamt, enra);

    #pragma unroll
    for(int i=0;i<2;i++){ float s = sw[334+i];
        #pragma unroll
        for(int c=0;c<4;c++) s += sw[326 + i*4 + c] * d4[c]; hl[i]=s; }
    float lpdg, endg; int dgrep; mcat<2>(hl, digm, lpdg, dgrep, endg);

    float lps = 0.f, ens = 0.f; int dir = 0, res = 0, amt = 0, rep = 0;
    switch(tt){
        case 0: lps = lpmv;               ens = enmv;               dir = mvdir; break;
        case 1: lps = lptd + lptr + lpta; ens = entd + entr + enta; dir = trdir; res = trres; amt = tramt; break;
        case 2: lps = lppr + lppa;        ens = enpr + enpa;        res = pkres; amt = pkamt; break;
        case 3: lps = lpdg;               ens = endg;               rep = dgrep; break;
        case 5: lps = lpra;               ens = enra;               amt = rcamt; break;
        default: break;
    }
    float tot_lp = t_lp + lps;
    float tot_en = t_en + ens;

    crm[q] = critic;
    lpm[q] = tot_lp;
    enm[q] = tot_en;

    out[96000 + q] = (fam != 0) ? (float)fact : 0.f;
    size_t ub = 390912 + (size_t)b*6*HW + p;
    out[ub + 0*HW] = um ? (float)tt  : 0.f;
    out[ub + 1*HW] = um ? (float)dir : 0.f;
    out[ub + 2*HW] = um ? (float)res : 0.f;
    out[ub + 3*HW] = um ? (float)amt : 0.f;
    out[ub + 4*HW] = um ? (float)rep : 0.f;
    out[ub + 5*HW] = um ? 1.f : 0.f;

    // scatter winner: numpy last-write-wins == max linear position per (b,id)
    if(um){
        int id = loc[((size_t)b*2 + 1)*HW + p] + 10;
        if((unsigned)id < 1000u) atomicMax(&idx[b*1000 + id], p);
    }
}

// ---------------- Kernel 5: resolve [B,1000] scatters ----------------
__global__ __launch_bounds__(256) void k_gather(const int* __restrict__ idx,
                                                const float* __restrict__ crm,
                                                const float* __restrict__ lpm,
                                                const float* __restrict__ enm,
                                                float* __restrict__ out){
    int j = blockIdx.x * 256 + threadIdx.x;
    if(j >= 32000) return;
    int b = j / 1000;
    int pos = idx[j];
    float lp = 0.f, cv = 0.f, en = 0.f;
    if(pos >= 0){
        size_t q = (size_t)b*HW + pos;
        lp = lpm[q]; cv = crm[q]; en = enm[q];
    }
    out[j]          = lp;
    out[32000 + j]  = cv;
    out[64000 + j]  = en;
}

extern "C" void kernel_launch(void* const* d_in, const int* in_sizes, int n_in,
                              void* d_out, int out_size, void* d_ws, size_t ws_size,
                              hipStream_t stream) {
    const float* mf  = (const float*)d_in[1];
    const float* ffp = (const float*)d_in[2];
    const float* ufp = (const float*)d_in[3];
    const int*   loc = (const int*)d_in[4];
    const int* vaM = (const int*)d_in[5];
    const int* vaT = (const int*)d_in[6];
    const int* vaP = (const int*)d_in[7];
    const int* vaD = (const int*)d_in[8];
    const int* vaS = (const int*)d_in[9];
    const int* vaR = (const int*)d_in[10];
    const int* vaN = (const int*)d_in[11];
    const int* vaF = (const int*)d_in[12];
    const float *Wf=(const float*)d_in[13], *bf=(const float*)d_in[14];
    const float *Wc=(const float*)d_in[15], *bc=(const float*)d_in[16];
    const float *Wdw=(const float*)d_in[17], *bdw=(const float*)d_in[18];
    const float *Wt=(const float*)d_in[19], *bt=(const float*)d_in[20];
    const float *Wmd=(const float*)d_in[21], *bmd=(const float*)d_in[22];
    const float *Wtd=(const float*)d_in[23], *btd=(const float*)d_in[24];
    const float *Wtr=(const float*)d_in[25], *btr=(const float*)d_in[26];
    const float *Wta=(const float*)d_in[27], *bta=(const float*)d_in[28];
    const float *Wpr=(const float*)d_in[29], *bpr=(const float*)d_in[30];
    const float *Wpa=(const float*)d_in[31], *bpa=(const float*)d_in[32];
    const float *Wra=(const float*)d_in[33], *bra=(const float*)d_in[34];
    const float *Wdr=(const float*)d_in[35], *bdr=(const float*)d_in[36];

    char* ws = (char*)d_ws;
    float* le  = (float*)(ws + 0);                 // 32*2*9216*4  = 2,359,296
    float* df  = (float*)(ws + 2359296);           // 32*4*9216*4  = 4,718,592
    float* crm = (float*)(ws + 7077888);           // 32*9216*4    = 1,179,648
    float* lpm = (float*)(ws + 8257536);
    float* enm = (float*)(ws + 9437184);
    int*   idx = (int*)(ws + 10616832);            // 32*1000*4    = 128,000
    unsigned* mm = (unsigned*)(ws + 10744832);     // 4+12 pad
    unsigned* tvm = (unsigned*)(ws + 10744848);    // 32*9216*4 = 1,179,648
    unsigned* pkd = (unsigned*)(ws + 11924496);    // 32*9216*4

    hipMemsetAsync(mm, 0x00, 8, stream);           // max accumulators -> encoded -inf floor
    hipMemsetAsync((char*)mm + 8, 0xFF, 8, stream);// min accumulators -> encoded +inf ceil
    hipMemsetAsync(idx, 0xFF, 128000, stream);     // scatter winners -> -1

    k_masks<<<dim3(288), dim3(256), 0, stream>>>(vaM, vaT, vaP, vaD, vaS, vaR, vaN, vaF, tvm, pkd);
    k_le<<<dim3(2304), dim3(256), 0, stream>>>(mf, le, mm);
    k_dirconv<<<dim3(1152), dim3(256), 0, stream>>>(ufp, le, mm, Wdw, bdw, df);
    k_heads<<<dim3(1152), dim3(256), 0, stream>>>(
        mf, ufp, ffp, loc, tvm, pkd,
        Wc, bc, Wf, bf, Wt, bt, Wmd, bmd, Wtd, btd, Wtr, btr,
        Wta, bta, Wpr, bpr, Wpa, bpa, Wra, bra, Wdr, bdr,
        df, crm, lpm, enm, idx, (float*)d_out);
    k_gather<<<dim3(125), dim3(256), 0, stream>>>(idx, crm, lpm, enm, (float*)d_out);
}

// Round 6
// 201.191 us; speedup vs baseline: 1.3653x; 1.0477x over previous
//
#include <hip/hip_runtime.h>
#include <hip/hip_bf16.h>

// Problem constants (B=32, H=W=96, D=5, R=5, A=10, K=2, FA=4, T=7)
#define HW 9216
#define NB 32
#define NPOS (NB*HW)   // 294912

// ---- float <-> order-preserving unsigned encoding for atomic min/max ----
__device__ inline unsigned fenc(float f){
    unsigned u = __float_as_uint(f);
    return (u & 0x80000000u) ? ~u : (u | 0x80000000u);
}
__device__ inline float fdec(unsigned u){
    return __uint_as_float((u & 0x80000000u) ? (u & 0x7fffffffu) : ~u);
}

// ---------------- Kernel 1: le = avgpool3x3(mf)+mf, global per-channel min/max ----------------
__global__ __launch_bounds__(256) void k_le(const float* __restrict__ mf,
                                            float* __restrict__ le,
                                            unsigned* __restrict__ mm /*[4]: max0,max1,min0,min1*/){
    int n = blockIdx.x * 256 + threadIdx.x;        // n < NB*2*HW
    int p = n % HW;
    int bc = n / HW;
    int c = bc & 1;
    int h = p / 96, w = p % 96;
    const float* plane = mf + (size_t)bc * HW;
    float s = 0.f;
    #pragma unroll
    for(int dy=-1; dy<=1; ++dy){
        int y = h + dy;
        if((unsigned)y < 96u){
            #pragma unroll
            for(int dx=-1; dx<=1; ++dx){
                int x = w + dx;
                if((unsigned)x < 96u) s += plane[y*96 + x];
            }
        }
    }
    float v = s * (1.0f/9.0f) + plane[p];
    le[n] = v;

    float mx = v, mn = v;
    #pragma unroll
    for(int o=32; o; o>>=1){
        mx = fmaxf(mx, __shfl_xor(mx, o));
        mn = fminf(mn, __shfl_xor(mn, o));
    }
    __shared__ float smx[4], smn[4];
    int wv = threadIdx.x >> 6;
    if((threadIdx.x & 63) == 0){ smx[wv] = mx; smn[wv] = mn; }
    __syncthreads();
    if(threadIdx.x == 0){
        for(int i=1;i<4;i++){ mx = fmaxf(mx, smx[i]); mn = fminf(mn, smn[i]); }
        atomicMax(&mm[c],     fenc(mx));
        atomicMin(&mm[2 + c], fenc(mn));
    }
}

// ---------------- Kernel 2: df = LeakyReLU(conv3x3([norm(le), uf], Wd) + bd) ----------------
__global__ __launch_bounds__(256) void k_dirconv(const float* __restrict__ uf,
                                                 const float* __restrict__ le,
                                                 const unsigned* __restrict__ mm,
                                                 const float* __restrict__ Wdw,
                                                 const float* __restrict__ bdw,
                                                 float* __restrict__ df){
    __shared__ float sW[180];
    __shared__ float sb[4];
    for(int i=threadIdx.x; i<180; i+=256) sW[i] = Wdw[i];
    if(threadIdx.x < 4) sb[threadIdx.x] = bdw[threadIdx.x];
    __syncthreads();

    int n = blockIdx.x * 256 + threadIdx.x;        // n < NB*HW
    int b = n / HW, p = n % HW;
    int h = p / 96, w = p % 96;

    float mx0 = fdec(mm[0]), mx1 = fdec(mm[1]);
    float mn0 = fdec(mm[2]), mn1 = fdec(mm[3]);
    float sc0 = 2.f / (mx0 - mn0), sc1 = 2.f / (mx1 - mn1);
    float of0 = -1.f - mn0 * sc0,  of1 = -1.f - mn1 * sc1;

    float acc0 = sb[0], acc1 = sb[1], acc2 = sb[2], acc3 = sb[3];
    #pragma unroll
    for(int i=0;i<5;i++){
        #pragma unroll
        for(int ky=0; ky<3; ky++){
            int y = h + ky - 1;
            if((unsigned)y >= 96u) continue;
            #pragma unroll
            for(int kx=0; kx<3; kx++){
                int x = w + kx - 1;
                if((unsigned)x >= 96u) continue;
                float v;
                if(i < 2) v = le[((size_t)b*2 + i)*HW + y*96 + x] * (i ? sc1 : sc0) + (i ? of1 : of0);
                else      v = uf[((size_t)b*3 + (i-2))*HW + y*96 + x];
                acc0 += v * sW[((0*5+i)*3+ky)*3+kx];
                acc1 += v * sW[((1*5+i)*3+ky)*3+kx];
                acc2 += v * sW[((2*5+i)*3+ky)*3+kx];
                acc3 += v * sW[((3*5+i)*3+ky)*3+kx];
            }
        }
    }
    size_t ob = ((size_t)b*4)*HW + p;
    df[ob + 0*HW] = acc0 > 0.f ? acc0 : 0.01f*acc0;
    df[ob + 1*HW] = acc1 > 0.f ? acc1 : 0.01f*acc1;
    df[ob + 2*HW] = acc2 > 0.f ? acc2 : 0.01f*acc2;
    df[ob + 3*HW] = acc3 > 0.f ? acc3 : 0.01f*acc3;
}

// ---------------- Kernel 3a: transfer-mask partial, one direction per blockIdx.y ----------------
// tvp[d][pos]: bits r=0..4 = any-over-A of va_transfer[b,d,r,a,pos]
__global__ __launch_bounds__(256, 4) void k_tv(const int* __restrict__ vaT,
                                               unsigned* __restrict__ tvp)
{
    int d  = blockIdx.y;
    int n4 = blockIdx.x * 256 + threadIdx.x;       // < NPOS/4
    int b  = n4 / (HW/4);
    int p0 = (n4 - b*(HW/4)) * 4;

    const int* base = vaT + ((size_t)b*250 + d*50)*HW + p0;
    unsigned o0=0,o1=0,o2=0,o3=0;
    for(int r=0; r<5; r++){
        int4 acc = *(const int4*)(base + (size_t)(r*10)*HW);
        #pragma unroll
        for(int a=1; a<10; a++){
            int4 t = *(const int4*)(base + (size_t)(r*10+a)*HW);
            acc.x|=t.x; acc.y|=t.y; acc.z|=t.z; acc.w|=t.w;
        }
        o0 |= (unsigned)(acc.x!=0) << r;
        o1 |= (unsigned)(acc.y!=0) << r;
        o2 |= (unsigned)(acc.z!=0) << r;
        o3 |= (unsigned)(acc.w!=0) << r;
    }
    *(uint4*)(tvp + (size_t)d*NPOS + (size_t)b*HW + p0) = make_uint4(o0,o1,o2,o3);
}

// ---------------- Kernel 3b: pickup/move/etc partials, slice per blockIdx.y ----------------
// slice 0: vaP -> pkm bits 5..9
// slice 1: vaM bits 0..4, vaD bits 10..11, vaS bit 12, vaR bit 13, vaN bit 14, vaF bits 15..18
__global__ __launch_bounds__(256, 4) void k_pk(
    const int* __restrict__ vaM, const int* __restrict__ vaP,
    const int* __restrict__ vaD, const int* __restrict__ vaS, const int* __restrict__ vaR,
    const int* __restrict__ vaN, const int* __restrict__ vaF,
    unsigned* __restrict__ pkp)
{
    int sl = blockIdx.y;
    int n4 = blockIdx.x * 256 + threadIdx.x;       // < NPOS/4
    int b  = n4 / (HW/4);
    int p0 = (n4 - b*(HW/4)) * 4;

    unsigned o0=0,o1=0,o2=0,o3=0;
    if(sl == 0){
        const int* vpb = vaP + (size_t)b*50*HW + p0;
        for(int r=0; r<5; r++){
            int4 acc = *(const int4*)(vpb + (size_t)(r*10)*HW);
            #pragma unroll
            for(int a=1; a<10; a++){
                int4 t = *(const int4*)(vpb + (size_t)(r*10+a)*HW);
                acc.x|=t.x; acc.y|=t.y; acc.z|=t.z; acc.w|=t.w;
            }
            o0 |= (unsigned)(acc.x!=0) << (5+r);
            o1 |= (unsigned)(acc.y!=0) << (5+r);
            o2 |= (unsigned)(acc.z!=0) << (5+r);
            o3 |= (unsigned)(acc.w!=0) << (5+r);
        }
    } else {
        const int* vmb = vaM + (size_t)b*10*HW + p0;
        #pragma unroll
        for(int d=0; d<5; d++){
            int4 k0 = *(const int4*)(vmb + (size_t)(2*d+0)*HW);
            int4 k1 = *(const int4*)(vmb + (size_t)(2*d+1)*HW);
            o0 |= (unsigned)((k0.x|k1.x)!=0) << d;
            o1 |= (unsigned)((k0.y|k1.y)!=0) << d;
            o2 |= (unsigned)((k0.z|k1.z)!=0) << d;
            o3 |= (unsigned)((k0.w|k1.w)!=0) << d;
        }
        {
            const int* vdb = vaD + (size_t)b*2*HW + p0;
            int4 k0 = *(const int4*)(vdb);
            int4 k1 = *(const int4*)(vdb + (size_t)HW);
            o0 |= ((unsigned)(k0.x!=0)<<10) | ((unsigned)(k1.x!=0)<<11);
            o1 |= ((unsigned)(k0.y!=0)<<10) | ((unsigned)(k1.y!=0)<<11);
            o2 |= ((unsigned)(k0.z!=0)<<10) | ((unsigned)(k1.z!=0)<<11);
            o3 |= ((unsigned)(k0.w!=0)<<10) | ((unsigned)(k1.w!=0)<<11);
        }
        {
            const int* vsb = vaS + (size_t)b*2*HW + p0;
            int4 k0 = *(const int4*)(vsb);
            int4 k1 = *(const int4*)(vsb + (size_t)HW);
            o0 |= (unsigned)((k0.x|k1.x)!=0)<<12; o1 |= (unsigned)((k0.y|k1.y)!=0)<<12;
            o2 |= (unsigned)((k0.z|k1.z)!=0)<<12; o3 |= (unsigned)((k0.w|k1.w)!=0)<<12;
        }
        {
            const int* vrb = vaR + (size_t)b*2*HW + p0;
            int4 k0 = *(const int4*)(vrb);
            int4 k1 = *(const int4*)(vrb + (size_t)HW);
            o0 |= (unsigned)((k0.x|k1.x)!=0)<<13; o1 |= (unsigned)((k0.y|k1.y)!=0)<<13;
            o2 |= (unsigned)((k0.z|k1.z)!=0)<<13; o3 |= (unsigned)((k0.w|k1.w)!=0)<<13;
        }
        {
            int4 k0 = *(const int4*)(vaN + (size_t)b*HW + p0);
            o0 |= (unsigned)(k0.x!=0)<<14; o1 |= (unsigned)(k0.y!=0)<<14;
            o2 |= (unsigned)(k0.z!=0)<<14; o3 |= (unsigned)(k0.w!=0)<<14;
        }
        {
            const int* vfb = vaF + (size_t)b*4*HW + p0;
            #pragma unroll
            for(int j=0; j<4; j++){
                int4 k = *(const int4*)(vfb + (size_t)j*HW);
                o0 |= (unsigned)(k.x!=0) << (15+j);
                o1 |= (unsigned)(k.y!=0) << (15+j);
                o2 |= (unsigned)(k.z!=0) << (15+j);
                o3 |= (unsigned)(k.w!=0) << (15+j);
            }
        }
    }
    *(uint4*)(pkp + (size_t)sl*NPOS + (size_t)b*HW + p0) = make_uint4(o0,o1,o2,o3);
}

// ---- masked categorical: lp at argmax, argmax (first max), entropy over valid ----
template<int N>
__device__ __forceinline__ void mcat(const float* x, unsigned mask, float& lp, int& a, float& en){
    float ml[N];
    #pragma unroll
    for(int i=0;i<N;i++) ml[i] = ((mask >> i) & 1u) ? x[i] : -1e9f;
    float m = ml[0]; int am = 0;
    #pragma unroll
    for(int i=1;i<N;i++) if(ml[i] > m){ m = ml[i]; am = i; }
    float S = 0.f, T = 0.f;
    #pragma unroll
    for(int i=0;i<N;i++){
        float d = ml[i] - m;
        float e = expf(d);         // invalid entries: exp(-1e9-m) == 0 exactly
        S += e; T += e * d;
    }
    float lS = logf(S);
    lp = -lS;                      // ml[argmax] == m  =>  lp = m - (m + log S)
    a  = am;
    en = lS - T / S;               // == -sum_valid p*lp  (exact when >=1 valid; unused otherwise)
}

// ---------------- Kernel 4: per-position heads (partial masks in) ----------------
__global__ __launch_bounds__(256) void k_heads(
    const float* __restrict__ mf, const float* __restrict__ uf, const float* __restrict__ ff,
    const int* __restrict__ loc,
    const unsigned* __restrict__ tvp, const unsigned* __restrict__ pkp,
    const float* Wc, const float* bc, const float* Wf, const float* bf,
    const float* Wt, const float* bt, const float* Wmd, const float* bmd,
    const float* Wtd, const float* btd, const float* Wtr, const float* btr,
    const float* Wta, const float* bta, const float* Wpr, const float* bpr,
    const float* Wpa, const float* bpa, const float* Wra, const float* bra,
    const float* Wdr, const float* bdr,
    const float* __restrict__ df,
    float* __restrict__ crm, float* __restrict__ lpm, float* __restrict__ enm,
    int* __restrict__ idx, float* __restrict__ out)
{
    __shared__ float sw[336];
    {
        int t = threadIdx.x;
        #define CPW(off, src, n) for(int i=t;i<(n);i+=256) sw[(off)+i]=(src)[i];
        CPW(0,Wc,5)    CPW(5,bc,1)    CPW(6,Wf,24)   CPW(30,bf,4)
        CPW(34,Wt,35)  CPW(69,bt,7)   CPW(76,Wmd,20) CPW(96,bmd,5)
        CPW(101,Wtd,20) CPW(121,btd,5) CPW(126,Wtr,20) CPW(146,btr,5)
        CPW(151,Wta,40) CPW(191,bta,10) CPW(201,Wpr,20) CPW(221,bpr,5)
        CPW(226,Wpa,40) CPW(266,bpa,10) CPW(276,Wra,40) CPW(316,bra,10)
        CPW(326,Wdr,8)  CPW(334,bdr,2)
        #undef CPW
    }
    __syncthreads();

    int n = blockIdx.x * 256 + threadIdx.x;        // n < NB*HW
    int b = n / HW, p = n % HW;
    size_t q = (size_t)b*HW + p;

    unsigned tv = tvp[q] | (tvp[NPOS + q] << 5) | (tvp[2*(size_t)NPOS + q] << 10)
                | (tvp[3*(size_t)NPOS + q] << 15) | (tvp[4*(size_t)NPOS + q] << 20);
    unsigned pk = pkp[q] | pkp[NPOS + q];
    unsigned mvm  = pk & 31u;
    unsigned pkm  = (pk >> 5) & 31u;
    unsigned digm = (pk >> 10) & 3u;
    unsigned sd1  = (pk >> 12) & 1u;
    unsigned rc1  = (pk >> 13) & 1u;
    unsigned dn1  = (pk >> 14) & 1u;
    unsigned fam  = (pk >> 15) & 15u;

    unsigned uat = (mvm ? 1u:0u) | ((tv ? 1u:0u)<<1) | ((pkm ? 1u:0u)<<2) | ((digm ? 1u:0u)<<3)
                 | (sd1<<4) | (rc1<<5) | (dn1<<6);
    bool um = (uat != 0);

    // features
    float vf5[5];
    vf5[0] = mf[((size_t)b*2+0)*HW + p];
    vf5[1] = mf[((size_t)b*2+1)*HW + p];
    vf5[2] = uf[((size_t)b*3+0)*HW + p];
    vf5[3] = uf[((size_t)b*3+1)*HW + p];
    vf5[4] = uf[((size_t)b*3+2)*HW + p];
    float d4[4];
    #pragma unroll
    for(int o=0;o<4;o++) d4[o] = df[((size_t)b*4+o)*HW + p];
    float f6[6];
    #pragma unroll
    for(int j=0;j<6;j++) f6[j] = ff[((size_t)b*6+j)*HW + p];

    // critic
    float critic = sw[5];
    #pragma unroll
    for(int c=0;c<5;c++) critic += sw[c] * vf5[c];

    // factory masked argmax
    int fact = 0; float fb = -3e38f;
    #pragma unroll
    for(int j=0;j<4;j++){
        float lg = sw[30+j];
        #pragma unroll
        for(int c=0;c<6;c++) lg += sw[6 + j*6 + c] * f6[c];
        float mlv = ((fam >> j) & 1u) ? lg : -1e9f;
        if(mlv > fb){ fb = mlv; fact = j; }
    }

    // act-type head
    float tl[7];
    #pragma unroll
    for(int i=0;i<7;i++){
        float s = sw[69+i];
        #pragma unroll
        for(int c=0;c<5;c++) s += sw[34 + i*5 + c] * vf5[c];
        tl[i] = s;
    }
    float t_lp, t_en; int tt;
    mcat<7>(tl, uat, t_lp, tt, t_en);

    float hl[10];

    #pragma unroll
    for(int i=0;i<5;i++){ float s = sw[96+i];
        #pragma unroll
        for(int c=0;c<4;c++) s += sw[76 + i*4 + c] * d4[c]; hl[i]=s; }
    float lpmv, enmv; int mvdir; mcat<5>(hl, mvm, lpmv, mvdir, enmv);

    #pragma unroll
    for(int i=0;i<5;i++){ float s = sw[121+i];
        #pragma unroll
        for(int c=0;c<4;c++) s += sw[101 + i*4 + c] * d4[c]; hl[i]=s; }
    unsigned trd = 0;
    #pragma unroll
    for(int d=0; d<5; d++) trd |= (unsigned)(((tv >> (5*d)) & 31u) != 0) << d;
    float lptd, entd; int trdir; mcat<5>(hl, trd, lptd, trdir, entd);

    #pragma unroll
    for(int i=0;i<5;i++){ float s = sw[146+i];
        #pragma unroll
        for(int c=0;c<4;c++) s += sw[126 + i*4 + c] * d4[c]; hl[i]=s; }
    float lptr, entr; int trres; mcat<5>(hl, (tv >> (trdir*5)) & 31u, lptr, trres, entr);

    #pragma unroll
    for(int i=0;i<10;i++){ float s = sw[191+i];
        #pragma unroll
        for(int c=0;c<4;c++) s += sw[151 + i*4 + c] * d4[c]; hl[i]=s; }
    float lpta, enta; int tramt; mcat<10>(hl, 0x3FFu, lpta, tramt, enta);

    #pragma unroll
    for(int i=0;i<5;i++){ float s = sw[221+i];
        #pragma unroll
        for(int c=0;c<4;c++) s += sw[201 + i*4 + c] * d4[c]; hl[i]=s; }
    float lppr, enpr; int pkres; mcat<5>(hl, pkm, lppr, pkres, enpr);

    #pragma unroll
    for(int i=0;i<10;i++){ float s = sw[266+i];
        #pragma unroll
        for(int c=0;c<4;c++) s += sw[226 + i*4 + c] * d4[c]; hl[i]=s; }
    float lppa, enpa; int pkamt; mcat<10>(hl, 0x3FFu, lppa, pkamt, enpa);

    #pragma unroll
    for(int i=0;i<10;i++){ float s = sw[316+i];
        #pragma unroll
        for(int c=0;c<4;c++) s += sw[276 + i*4 + c] * d4[c]; hl[i]=s; }
    float lpra, enra; int rcamt; mcat<10>(hl, 0x3FFu, lpra, rcamt, enra);

    #pragma unroll
    for(int i=0;i<2;i++){ float s = sw[334+i];
        #pragma unroll
        for(int c=0;c<4;c++) s += sw[326 + i*4 + c] * d4[c]; hl[i]=s; }
    float lpdg, endg; int dgrep; mcat<2>(hl, digm, lpdg, dgrep, endg);

    float lps = 0.f, ens = 0.f; int dir = 0, res = 0, amt = 0, rep = 0;
    switch(tt){
        case 0: lps = lpmv;               ens = enmv;               dir = mvdir; break;
        case 1: lps = lptd + lptr + lpta; ens = entd + entr + enta; dir = trdir; res = trres; amt = tramt; break;
        case 2: lps = lppr + lppa;        ens = enpr + enpa;        res = pkres; amt = pkamt; break;
        case 3: lps = lpdg;               ens = endg;               rep = dgrep; break;
        case 5: lps = lpra;               ens = enra;               amt = rcamt; break;
        default: break;
    }
    float tot_lp = t_lp + lps;
    float tot_en = t_en + ens;

    crm[q] = critic;
    lpm[q] = tot_lp;
    enm[q] = tot_en;

    out[96000 + q] = (fam != 0) ? (float)fact : 0.f;
    size_t ub = 390912 + (size_t)b*6*HW + p;
    out[ub + 0*HW] = um ? (float)tt  : 0.f;
    out[ub + 1*HW] = um ? (float)dir : 0.f;
    out[ub + 2*HW] = um ? (float)res : 0.f;
    out[ub + 3*HW] = um ? (float)amt : 0.f;
    out[ub + 4*HW] = um ? (float)rep : 0.f;
    out[ub + 5*HW] = um ? 1.f : 0.f;

    // scatter winner: numpy last-write-wins == max linear position per (b,id)
    if(um){
        int id = loc[((size_t)b*2 + 1)*HW + p] + 10;
        if((unsigned)id < 1000u) atomicMax(&idx[b*1000 + id], p);
    }
}

// ---------------- Kernel 5: resolve [B,1000] scatters ----------------
__global__ __launch_bounds__(256) void k_gather(const int* __restrict__ idx,
                                                const float* __restrict__ crm,
                                                const float* __restrict__ lpm,
                                                const float* __restrict__ enm,
                                                float* __restrict__ out){
    int j = blockIdx.x * 256 + threadIdx.x;
    if(j >= 32000) return;
    int b = j / 1000;
    int pos = idx[j];
    float lp = 0.f, cv = 0.f, en = 0.f;
    if(pos >= 0){
        size_t q = (size_t)b*HW + pos;
        lp = lpm[q]; cv = crm[q]; en = enm[q];
    }
    out[j]          = lp;
    out[32000 + j]  = cv;
    out[64000 + j]  = en;
}

extern "C" void kernel_launch(void* const* d_in, const int* in_sizes, int n_in,
                              void* d_out, int out_size, void* d_ws, size_t ws_size,
                              hipStream_t stream) {
    const float* mf  = (const float*)d_in[1];
    const float* ffp = (const float*)d_in[2];
    const float* ufp = (const float*)d_in[3];
    const int*   loc = (const int*)d_in[4];
    const int* vaM = (const int*)d_in[5];
    const int* vaT = (const int*)d_in[6];
    const int* vaP = (const int*)d_in[7];
    const int* vaD = (const int*)d_in[8];
    const int* vaS = (const int*)d_in[9];
    const int* vaR = (const int*)d_in[10];
    const int* vaN = (const int*)d_in[11];
    const int* vaF = (const int*)d_in[12];
    const float *Wf=(const float*)d_in[13], *bf=(const float*)d_in[14];
    const float *Wc=(const float*)d_in[15], *bc=(const float*)d_in[16];
    const float *Wdw=(const float*)d_in[17], *bdw=(const float*)d_in[18];
    const float *Wt=(const float*)d_in[19], *bt=(const float*)d_in[20];
    const float *Wmd=(const float*)d_in[21], *bmd=(const float*)d_in[22];
    const float *Wtd=(const float*)d_in[23], *btd=(const float*)d_in[24];
    const float *Wtr=(const float*)d_in[25], *btr=(const float*)d_in[26];
    const float *Wta=(const float*)d_in[27], *bta=(const float*)d_in[28];
    const float *Wpr=(const float*)d_in[29], *bpr=(const float*)d_in[30];
    const float *Wpa=(const float*)d_in[31], *bpa=(const float*)d_in[32];
    const float *Wra=(const float*)d_in[33], *bra=(const float*)d_in[34];
    const float *Wdr=(const float*)d_in[35], *bdr=(const float*)d_in[36];

    char* ws = (char*)d_ws;
    float* le  = (float*)(ws + 0);                 // 32*2*9216*4  = 2,359,296
    float* df  = (float*)(ws + 2359296);           // 32*4*9216*4  = 4,718,592
    float* crm = (float*)(ws + 7077888);           // 32*9216*4    = 1,179,648
    float* lpm = (float*)(ws + 8257536);
    float* enm = (float*)(ws + 9437184);
    int*   idx = (int*)(ws + 10616832);            // 32*1000*4    = 128,000
    unsigned* mm = (unsigned*)(ws + 10744832);     // 16 B
    unsigned* tvp = (unsigned*)(ws + 10744848);    // 5*NPOS*4 = 5,898,240
    unsigned* pkp = (unsigned*)(ws + 16643088);    // 2*NPOS*4 = 2,359,296  (end ~19.0 MB)

    hipMemsetAsync(mm, 0x00, 8, stream);           // max accumulators -> encoded -inf floor
    hipMemsetAsync((char*)mm + 8, 0xFF, 8, stream);// min accumulators -> encoded +inf ceil
    hipMemsetAsync(idx, 0xFF, 128000, stream);     // scatter winners -> -1

    k_tv<<<dim3(288, 5), dim3(256), 0, stream>>>(vaT, tvp);
    k_pk<<<dim3(288, 2), dim3(256), 0, stream>>>(vaM, vaP, vaD, vaS, vaR, vaN, vaF, pkp);
    k_le<<<dim3(2304), dim3(256), 0, stream>>>(mf, le, mm);
    k_dirconv<<<dim3(1152), dim3(256), 0, stream>>>(ufp, le, mm, Wdw, bdw, df);
    k_heads<<<dim3(1152), dim3(256), 0, stream>>>(
        mf, ufp, ffp, loc, tvp, pkp,
        Wc, bc, Wf, bf, Wt, bt, Wmd, bmd, Wtd, btd, Wtr, btr,
        Wta, bta, Wpr, bpr, Wpa, bpa, Wra, bra, Wdr, bdr,
        df, crm, lpm, enm, idx, (float*)d_out);
    k_gather<<<dim3(125), dim3(256), 0, stream>>>(idx, crm, lpm, enm, (float*)d_out);
}